// Round 13
// baseline (303.074 us; speedup 1.0000x reference)
//
#include <hip/hip_runtime.h>
#include <hip/hip_bf16.h>

using bf16x8 = __attribute__((ext_vector_type(8))) short;
using f32x4  = __attribute__((ext_vector_type(4))) float;

constexpr int cV  = 50257;
constexpr int cVp = 50688;          // padded rows for bf16 W (99*512)
constexpr int cD  = 128;
constexpr int cN  = 512;
constexpr int cS  = 256;

#define PHI_F    1.6180339887498949f
#define INV2PI_F 0.15915494309189535f
#define SQRT2_F  1.4142135623730951f

__device__ __forceinline__ float fract1(float x) { return x - floorf(x); }

#if __has_builtin(__builtin_amdgcn_sinf)
__device__ __forceinline__ float sin_rev(float r) { return __builtin_amdgcn_sinf(r); }   // sin(2*pi*r)
__device__ __forceinline__ float cos_rev(float r) { return __builtin_amdgcn_cosf(r); }   // cos(2*pi*r)
#else
__device__ __forceinline__ float sin_rev(float r) { return __sinf(r * 6.2831853071795865f); }
__device__ __forceinline__ float cos_rev(float r) { return __cosf(r * 6.2831853071795865f); }
#endif

#if __has_builtin(__builtin_amdgcn_rcpf)
__device__ __forceinline__ float fast_rcp(float x) { return __builtin_amdgcn_rcpf(x); }
#else
__device__ __forceinline__ float fast_rcp(float x) { return 1.f / x; }
#endif

__device__ __forceinline__ unsigned short f2bf(float f) {
  unsigned u = __float_as_uint(f);
  unsigned r = (u + 0x7FFFu + ((u >> 16) & 1u)) >> 16;
  return (unsigned short)r;
}

// ---- k_front: block 0 = scan (inline emb gather); 1..512 = proj transpose;
// ---- 513..576 = fvG precompute; 577..3744 = W bf16 pack. ONE dispatch.
__global__ __launch_bounds__(256) void k_front(const int* __restrict__ tokens,
                                               const float* __restrict__ emb,
                                               const float* __restrict__ pr, const float* __restrict__ pi,
                                               float* __restrict__ pTR, float* __restrict__ pTI,
                                               const float* __restrict__ Wf, const float* __restrict__ Bf,
                                               float2* __restrict__ fvG,
                                               const float* __restrict__ W, unsigned short* __restrict__ Wbf,
                                               float* __restrict__ states) {
  int blk = blockIdx.x;
  int tid = threadIdx.x;
  if (blk == 0) {
    // ---- sequential scan, mc computed inline from emb (prefetch depth 8) ----
    int b = tid >> 7, d = tid & 127;
    float2 buf[8];                                  // (m2, c)
#pragma unroll
    for (int i = 0; i < 8; ++i) {
      int tok = tokens[b * cS + i];
      float w  = emb[tok * (2 * cD) + d];
      float be = emb[tok * (2 * cD) + cD + d];
      buf[i] = make_float2(SQRT2_F * INV2PI_F * fast_rcp(1.f + fabsf(w)),
                           fmaf((float)i, PHI_F, be) * INV2PI_F + 0.125f);
    }
    float sv = 0.f;
    float* out = states + (b * cS) * cD + d;
#pragma unroll 8
    for (int s = 0; s < cS; ++s) {
      float2 v = buf[s & 7];
      if (s + 8 < cS) {
        int tok = tokens[b * cS + s + 8];
        float w  = emb[tok * (2 * cD) + d];
        float be = emb[tok * (2 * cD) + cD + d];
        buf[s & 7] = make_float2(SQRT2_F * INV2PI_F * fast_rcp(1.f + fabsf(w)),
                                 fmaf((float)(s + 8), PHI_F, be) * INV2PI_F + 0.125f);
      }
      float r = fmaf(sv, v.x, v.y);
      sv = sin_rev(fract1(r));
      out[s * cD] = sv * SQRT2_F;
    }
  } else if (blk <= 512) {
    int idx = (blk - 1) * 256 + tid;               // L*N*D = 131072
    int l = idx >> 16, rem = idx & 65535;
    int n = rem >> 7, d = rem & 127;
    int src = (l * cD + d) * cN + n;
    pTR[idx] = pr[src];
    pTI[idx] = pi[src];
  } else if (blk <= 576) {
    int base = (blk - 513) * 2048;                 // 64 blocks x 2048 = 131072
#pragma unroll
    for (int i = 0; i < 8; ++i) {
      int idx = base + i * 256 + tid;
      float w = Wf[idx], bf = Bf[idx];
      fvG[idx] = make_float2(INV2PI_F * fast_rcp(1.f + fabsf(w)), bf * INV2PI_F);
    }
  } else {
    int idx = (blk - 577) * 256 + tid;             // cVp rows * 16
    int row = idx >> 4, c0 = (idx & 15) * 8;
    ushort4 o0 = {0,0,0,0}, o1 = {0,0,0,0};
    if (row < cV) {
      float4 w0 = *(const float4*)(W + (size_t)row * cD + c0);
      float4 w1 = *(const float4*)(W + (size_t)row * cD + c0 + 4);
      o0 = { f2bf(w0.x), f2bf(w0.y), f2bf(w0.z), f2bf(w0.w) };
      o1 = { f2bf(w1.x), f2bf(w1.y), f2bf(w1.z), f2bf(w1.w) };
    }
    unsigned short* dst = Wbf + (size_t)row * cD + c0;
    *(ushort4*)dst = o0;
    *(ushort4*)(dst + 4) = o1;
  }
}

// ---- k_tok2: per-layer fused attn + fsum + res for 2 tokens per block ------
// grid 256 (b x 128 qp), 512 thr. Attn/res phases = R10 k_tok (correctness-proven);
// fsum = k_layer-style: LDS-chunked fvG staging, private accumulation, 3-shuffle reduce.
__global__ __launch_bounds__(512) void k_tok2(const float* __restrict__ x, const float* __restrict__ states,
                                              const float* __restrict__ wq, const float* __restrict__ bq,
                                              const float* __restrict__ wk, const float* __restrict__ bk,
                                              const float2* __restrict__ fvG,
                                              const float* __restrict__ pTR, const float* __restrict__ pTI,
                                              const float* __restrict__ w_out, const float* __restrict__ b_out,
                                              const float* __restrict__ osc_p,
                                              const float* __restrict__ attn_s, const float* __restrict__ res_s,
                                              float* __restrict__ xout, unsigned short* __restrict__ xbf) {
  __shared__ __align__(16) float qrow[2][256];
  __shared__ __align__(16) float rkl[128], bkl[128];
  __shared__ float Psum[2][256];
  __shared__ float redm[2][4], reds[2][4];
  __shared__ float cred[2][256];
  __shared__ __align__(16) float xl[2][128];
  __shared__ __align__(16) float ctxl[2][128];
  __shared__ float uvU[2][512], uvV[2][512];
  __shared__ __align__(16) float4 part[2][8][32];
  __shared__ __align__(16) float2 fchunk[32][129];
  int blk = blockIdx.x;
  int b = blk >> 7, qp = blk & 127;
  int tid = threadIdx.x;
  int sub = tid >> 8, t = tid & 255;
  int q = qp * 2 + sub;
  // ---- phase A0: params, Q rows, x rows ----
  if (tid < 128) {
    rkl[tid] = INV2PI_F / (1.f + fabsf(wk[tid]));
    bkl[tid] = bk[tid] * INV2PI_F;
  }
  if (t < 128) {
    float xv = x[(b * cS + q) * cD + t];
    xl[sub][t] = xv;
    float rq = 1.f / (1.f + fabsf(wq[t]));
    float thq = fmaf(xv, rq, fmaf((float)q, PHI_F, bq[t])) * INV2PI_F;
    float fq = fract1(thq);
    qrow[sub][t]       = cos_rev(fq);
    qrow[sub][128 + t] = sin_rev(fq);
  }
  Psum[sub][t] = 0.f;
  __syncthreads();
  // ---- phase A1: scores (thread t = key position) ----
  bool act = (t <= q);
  float sc[8];
  const float4* Sr = (const float4*)(states + (b * cS + t) * cD);
#pragma unroll
  for (int h = 0; h < 8; ++h) {
    float sacc = 0.f;
#pragma unroll
    for (int j = 0; j < 4; ++j) {
      float4 sv4 = Sr[h * 4 + j];
      int hd = h * 16 + j * 4;
      float sva[4] = { sv4.x, sv4.y, sv4.z, sv4.w };
#pragma unroll
      for (int c = 0; c < 4; ++c) {
        float f = fract1(fmaf(sva[c], rkl[hd + c], bkl[hd + c]));
        float ck = cos_rev(f), sk = sin_rev(f);
        sacc = fmaf(qrow[sub][hd + c], ck, fmaf(qrow[sub][128 + hd + c], sk, sacc));
      }
    }
    sc[h] = act ? sacc * 0.17677669529663689f : -3.0e38f;   // 1/sqrt(2*DH)
  }
  // ---- phase A2: softmax ----
  int wid = t >> 6;
  for (int h = 0; h < 8; ++h) {
    float v = sc[h];
#pragma unroll
    for (int off = 32; off; off >>= 1) v = fmaxf(v, __shfl_xor(v, off, 64));
    if ((t & 63) == 0) redm[sub][wid] = v;
    __syncthreads();
    float m = fmaxf(fmaxf(redm[sub][0], redm[sub][1]), fmaxf(redm[sub][2], redm[sub][3]));
    float p = act ? __expf(sc[h] - m) : 0.f;
    float ps = p;
#pragma unroll
    for (int off = 32; off; off >>= 1) ps += __shfl_xor(ps, off, 64);
    if ((t & 63) == 0) reds[sub][wid] = ps;
    __syncthreads();
    float tot = reds[sub][0] + reds[sub][1] + reds[sub][2] + reds[sub][3];
    Psum[sub][t] += p / tot;
  }
  __syncthreads();
  // ---- phase A3: context -> ctxl ----
  {
    int d = t & 127, half = t >> 7;
    float acc = 0.f;
    int k0 = half * 128;
    int kend = min(k0 + 128, q + 1);
    for (int kk = k0; kk < kend; ++kk)
      acc = fmaf(Psum[sub][kk], states[(b * cS + kk) * cD + d], acc);
    cred[sub][t] = acc;
    __syncthreads();
    if (half == 0) ctxl[sub][d] = cred[sub][t] + cred[sub][t + 128];
  }
  // ---- phase B: fsum, 16 chunks of 32 n-rows; thread = (nl, tok, dq) ----
  {
    int nl  = tid >> 4;                             // 0..31
    int tok = (tid >> 3) & 1;
    int dq  = tid & 7;
    float srev = (float)(qp * 2 + tok) * INV2PI_F;
    for (int ch = 0; ch < 16; ++ch) {
      int n0 = ch * 32;
      const float2* src = fvG + n0 * cD;
#pragma unroll
      for (int i = 0; i < 8; ++i) {
        int idx = tid + i * 512;                    // 4096 = 32 rows x 128 d
        int r = idx >> 7, dcol = idx & 127;
        fchunk[r][dcol] = src[r * cD + dcol];
      }
      __syncthreads();
      float uc = 0.f, us = 0.f;
#pragma unroll
      for (int i = 0; i < 16; ++i) {
        int d = i * 8 + dq;
        float2 f = fchunk[nl][d];
        float fr = fract1(fmaf(xl[tok][d], f.x, f.y + srev));
        uc += cos_rev(fr);
        us += sin_rev(fr);
      }
      uc += __shfl_xor(uc, 1, 64); us += __shfl_xor(us, 1, 64);
      uc += __shfl_xor(uc, 2, 64); us += __shfl_xor(us, 2, 64);
      uc += __shfl_xor(uc, 4, 64); us += __shfl_xor(us, 4, 64);
      if (dq == 0) { uvU[tok][n0 + nl] = uc; uvV[tok][n0 + nl] = us; }
      __syncthreads();
    }
  }
  // ---- phase C: res projection + combine (R10 structure) ----
  {
    int r8 = tid & 255;
    int d4 = r8 & 31, nh = r8 >> 5;                 // 8 n-chunks of 64
    float a0 = 0.f, a1 = 0.f, a2 = 0.f, a3 = 0.f;
    const float* prB = pTR + d4 * 4;
    const float* piB = pTI + d4 * 4;
    int n0 = nh * 64;
#pragma unroll 4
    for (int n = n0; n < n0 + 64; ++n) {
      float4 pr = *(const float4*)(prB + n * cD);
      float4 pi = *(const float4*)(piB + n * cD);
      float wr = uvU[sub][n], wi = uvV[sub][n];
      a0 = fmaf(wr, pr.x, fmaf(wi, pi.x, a0));
      a1 = fmaf(wr, pr.y, fmaf(wi, pi.y, a1));
      a2 = fmaf(wr, pr.z, fmaf(wi, pi.z, a2));
      a3 = fmaf(wr, pr.w, fmaf(wi, pi.w, a3));
    }
    part[sub][nh][d4] = make_float4(a0, a1, a2, a3);
    __syncthreads();
    if (nh == 0) {
      float rr[4] = { 0.f, 0.f, 0.f, 0.f };
#pragma unroll
      for (int j = 0; j < 8; ++j) {
        float4 p = part[sub][j][d4];
        rr[0] += p.x; rr[1] += p.y; rr[2] += p.z; rr[3] += p.w;
      }
      int di = d4 * 4;
      float4 cx  = *(const float4*)&ctxl[sub][di];
      float4 wo  = *(const float4*)(w_out + di);
      float4 bo  = *(const float4*)(b_out + di);
      float4 os4 = *(const float4*)(osc_p + di);
      float4 xv  = *(const float4*)&xl[sub][di];
      float as = attn_s[0], rs = res_s[0];
      float sphi = (float)q * PHI_F;
      float cxa[4] = { cx.x, cx.y, cx.z, cx.w };
      float woa[4] = { wo.x, wo.y, wo.z, wo.w };
      float boa[4] = { bo.x, bo.y, bo.z, bo.w };
      float osa[4] = { os4.x, os4.y, os4.z, os4.w };
      float xva[4] = { xv.x, xv.y, xv.z, xv.w };
      float oa[4];
#pragma unroll
      for (int c = 0; c < 4; ++c) {
        float th = fmaf(cxa[c], 1.f / (1.f + fabsf(woa[c])), boa[c]) + sphi;
        float f = fract1(th * INV2PI_F);
        float ao = osa[c] * (cos_rev(f) + sin_rev(f));
        float r = rr[c];
        float sil = r / (1.f + __expf(-r));
        oa[c] = fmaf(as, ao, fmaf(rs, sil, xva[c]));
      }
      *(float4*)(xout + (b * cS + q) * cD + di) = make_float4(oa[0], oa[1], oa[2], oa[3]);
      if (xbf) {
        ushort4 b4 = { f2bf(oa[0]), f2bf(oa[1]), f2bf(oa[2]), f2bf(oa[3]) };
        *(ushort4*)(xbf + (b * cS + q) * cD + di) = b4;
      }
    }
  }
}

// ---------------- final logits GEMM: R9 champion (G*) ------------------------
// grid 792 = 8 m-chunks (outer) x 99 v-chunks of 512 cols. 256 thr = 4 waves.
// Block = 64 m x 512 v; wave = 64 m x 128 v (fm=4, fv=8; acc 128 VGPR).
// Epilogue: per-wave LDS transpose -> full-wave float4 stores (2 rows x 512B).
__global__ __launch_bounds__(256) void k_gemm(const unsigned short* __restrict__ Xbf,
                                              const unsigned short* __restrict__ Wbf,
                                              float* __restrict__ out) {
  __shared__ __align__(16) float Cst[4][16 * 132];
  int t = threadIdx.x;
  int mchunk = blockIdx.x / 99, vchunk = blockIdx.x % 99;
  int m0 = mchunk * 64;
  int v0 = vchunk * 512;
  int wid = t >> 6, lane = t & 63, lr = lane & 15, lk = lane >> 4;
  int wv = wid * 128;
  const bf16x8* Xp = (const bf16x8*)Xbf;            // row-major: row*16 + ks*4 + lk
  const bf16x8* Wp = (const bf16x8*)Wbf;
  f32x4 acc[4][8];
#pragma unroll
  for (int fm = 0; fm < 4; ++fm)
#pragma unroll
    for (int fv = 0; fv < 8; ++fv) acc[fm][fv] = (f32x4){0.f, 0.f, 0.f, 0.f};
#pragma unroll
  for (int ks = 0; ks < 4; ++ks) {
    bf16x8 a[4];
#pragma unroll
    for (int fm = 0; fm < 4; ++fm)
      a[fm] = Xp[(m0 + fm * 16 + lr) * 16 + ks * 4 + lk];
#pragma unroll
    for (int fv = 0; fv < 8; ++fv) {
      bf16x8 b = Wp[(size_t)(v0 + wv + fv * 16 + lr) * 16 + ks * 4 + lk];
#pragma unroll
      for (int fm = 0; fm < 4; ++fm)
        acc[fm][fv] = __builtin_amdgcn_mfma_f32_16x16x32_bf16(a[fm], b, acc[fm][fv], 0, 0, 0);
    }
  }
  float* Cp = &Cst[wid][0];
  int row2b = lane >> 5;
  int colg  = (lane & 31) * 4;
#pragma unroll
  for (int fm = 0; fm < 4; ++fm) {
#pragma unroll
    for (int fv = 0; fv < 8; ++fv)
#pragma unroll
      for (int r = 0; r < 4; ++r)
        Cp[(lk * 4 + r) * 132 + fv * 16 + lr] = acc[fm][fv][r];
#pragma unroll
    for (int step = 0; step < 8; ++step) {
      int rowl = step * 2 + row2b;
      float4 cv = *(const float4*)&Cp[rowl * 132 + colg];
      size_t rb = (size_t)(m0 + fm * 16 + rowl) * cV;
      int cb = v0 + wv + colg;
      if (cb + 3 < cV) {
        *(float4*)(out + rb + cb) = cv;
      } else {
        float ca[4] = { cv.x, cv.y, cv.z, cv.w };
#pragma unroll
        for (int j = 0; j < 4; ++j)
          if (cb + j < cV) out[rb + cb + j] = ca[j];
      }
    }
  }
}

extern "C" void kernel_launch(void* const* d_in, const int* in_sizes, int n_in,
                              void* d_out, int out_size, void* d_ws, size_t ws_size,
                              hipStream_t stream) {
  const int*   tokens    = (const int*)d_in[0];
  const float* emb       = (const float*)d_in[1];
  const float* wq        = (const float*)d_in[2];
  const float* bq        = (const float*)d_in[3];
  const float* wk        = (const float*)d_in[4];
  const float* bk        = (const float*)d_in[5];
  const float* w_out     = (const float*)d_in[6];
  const float* b_out     = (const float*)d_in[7];
  const float* out_scale = (const float*)d_in[8];
  const float* Wf        = (const float*)d_in[9];
  const float* Bf        = (const float*)d_in[10];
  const float* pr        = (const float*)d_in[11];
  const float* pi        = (const float*)d_in[12];
  const float* attn_s    = (const float*)d_in[13];
  const float* res_s     = (const float*)d_in[14];
  const float* out_proj  = (const float*)d_in[15];
  float* out = (float*)d_out;
  float* ws  = (float*)d_ws;

  float*  states = ws;                          // 65536
  float*  x1     = ws + 65536;                  // 65536
  float*  x2     = ws + 131072;                 // 65536
  float*  pTR    = ws + 196608;                 // 131072
  float*  pTI    = ws + 327680;                 // 131072
  float2* fvG    = (float2*)(ws + 458752);      // 131072 float2 (262144 floats)
  unsigned short* X2bf = (unsigned short*)(ws + 720896);  // 65536 ushorts
  unsigned short* Wbf  = (unsigned short*)(ws + 753664);  // 50688*128 ushorts (13.0MB)

  k_front<<<577 + (cVp * 16) / 256, 256, 0, stream>>>(tokens, emb, pr, pi, pTR, pTI,
                                                      Wf, Bf, fvG, out_proj, Wbf, states);

  const float* xin = states;
  float* xouts[2] = { x1, x2 };
  for (int l = 0; l < 2; ++l) {
    k_tok2<<<256, 512, 0, stream>>>(xin, states,
                                    wq + l * 128, bq + l * 128, wk + l * 128, bk + l * 128,
                                    fvG + l * 65536,
                                    pTR + l * 65536, pTI + l * 65536,
                                    w_out + l * 128, b_out + l * 128, out_scale + l * 128,
                                    attn_s + l, res_s + l,
                                    xouts[l], (l == 1) ? X2bf : (unsigned short*)nullptr);
    xin = xouts[l];
  }
  k_gemm<<<8 * 99, 256, 0, stream>>>(X2bf, Wbf, out);
}

// Round 14
// 201.193 us; speedup vs baseline: 1.5064x; 1.5064x over previous
//
#include <hip/hip_runtime.h>
#include <hip/hip_bf16.h>

using bf16x8 = __attribute__((ext_vector_type(8))) short;
using f32x4  = __attribute__((ext_vector_type(4))) float;

constexpr int cV  = 50257;
constexpr int cVp = 50688;          // padded rows for bf16 W (99*512)
constexpr int cD  = 128;
constexpr int cN  = 512;
constexpr int cS  = 256;

#define PHI_F    1.6180339887498949f
#define INV2PI_F 0.15915494309189535f
#define SQRT2_F  1.4142135623730951f

__device__ __forceinline__ float fract1(float x) { return x - floorf(x); }

#if __has_builtin(__builtin_amdgcn_sinf)
__device__ __forceinline__ float sin_rev(float r) { return __builtin_amdgcn_sinf(r); }   // sin(2*pi*r)
__device__ __forceinline__ float cos_rev(float r) { return __builtin_amdgcn_cosf(r); }   // cos(2*pi*r)
#else
__device__ __forceinline__ float sin_rev(float r) { return __sinf(r * 6.2831853071795865f); }
__device__ __forceinline__ float cos_rev(float r) { return __cosf(r * 6.2831853071795865f); }
#endif

#if __has_builtin(__builtin_amdgcn_rcpf)
__device__ __forceinline__ float fast_rcp(float x) { return __builtin_amdgcn_rcpf(x); }
#else
__device__ __forceinline__ float fast_rcp(float x) { return 1.f / x; }
#endif

__device__ __forceinline__ unsigned short f2bf(float f) {
  unsigned u = __float_as_uint(f);
  unsigned r = (u + 0x7FFFu + ((u >> 16) & 1u)) >> 16;
  return (unsigned short)r;
}

// ---- k_setup: mc prep (0-255) + proj transpose (256-767) + fvG (768-831)
// ----          + W bf16 pack (832+). All massively parallel (emb gather too).
__global__ __launch_bounds__(256) void k_setup(const int* __restrict__ tokens,
                                               const float* __restrict__ emb,
                                               float2* __restrict__ mc,
                                               const float* __restrict__ pr, const float* __restrict__ pi,
                                               float* __restrict__ pTR, float* __restrict__ pTI,
                                               const float* __restrict__ Wf, const float* __restrict__ Bf,
                                               float2* __restrict__ fvG,
                                               const float* __restrict__ W, unsigned short* __restrict__ Wbf) {
  int blk = blockIdx.x;
  int tid = threadIdx.x;
  if (blk < 256) {
    int idx = blk * 256 + tid;                     // 65536 = S * (B*D)
    int t = idx & 255, s = idx >> 8;
    int b = t >> 7, d = t & 127;
    int tok = tokens[b * cS + s];
    float w  = emb[tok * (2 * cD) + d];
    float be = emb[tok * (2 * cD) + cD + d];
    float m2 = SQRT2_F * INV2PI_F * fast_rcp(1.f + fabsf(w));
    float c  = fmaf((float)s, PHI_F, be) * INV2PI_F + 0.125f;
    mc[idx] = make_float2(m2, c);
  } else if (blk < 768) {
    int idx = (blk - 256) * 256 + tid;             // L*N*D = 131072
    int l = idx >> 16, rem = idx & 65535;
    int n = rem >> 7, d = rem & 127;
    int src = (l * cD + d) * cN + n;
    pTR[idx] = pr[src];
    pTI[idx] = pi[src];
  } else if (blk < 832) {
    int base = (blk - 768) * 2048;                 // 64 blocks x 2048 = 131072
#pragma unroll
    for (int i = 0; i < 8; ++i) {
      int idx = base + i * 256 + tid;
      float w = Wf[idx], bf = Bf[idx];
      fvG[idx] = make_float2(INV2PI_F * fast_rcp(1.f + fabsf(w)), bf * INV2PI_F);
    }
  } else {
    int idx = (blk - 832) * 256 + tid;             // cVp rows * 16
    int row = idx >> 4, c0 = (idx & 15) * 8;
    ushort4 o0 = {0,0,0,0}, o1 = {0,0,0,0};
    if (row < cV) {
      float4 w0 = *(const float4*)(W + (size_t)row * cD + c0);
      float4 w1 = *(const float4*)(W + (size_t)row * cD + c0 + 4);
      o0 = { f2bf(w0.x), f2bf(w0.y), f2bf(w0.z), f2bf(w0.w) };
      o1 = { f2bf(w1.x), f2bf(w1.y), f2bf(w1.z), f2bf(w1.w) };
    }
    unsigned short* dst = Wbf + (size_t)row * cD + c0;
    *(ushort4*)dst = o0;
    *(ushort4*)(dst + 4) = o1;
  }
}

// ---------------- sequential scan (mc L2-hot, 8-deep prefetch) ---------------
__global__ void k_scan(const float2* __restrict__ mc, float* __restrict__ states) {
  int t = threadIdx.x;                              // 256 = B*D
  int b = t >> 7, d = t & 127;
  float2 buf[8];
#pragma unroll
  for (int i = 0; i < 8; ++i) buf[i] = mc[i * 256 + t];
  float sv = 0.f;
  float* out = states + (b * cS) * cD + d;
#pragma unroll 8
  for (int s = 0; s < cS; ++s) {
    float2 v = buf[s & 7];
    if (s + 8 < cS) buf[s & 7] = mc[(s + 8) * 256 + t];
    float r = fmaf(sv, v.x, v.y);
    sv = sin_rev(fract1(r));
    out[s * cD] = sv * SQRT2_F;
  }
}

// ---- k_tok2: per-layer fused attn + fsum + res for 2 tokens per block ------
// grid 256 (b x 128 qp), 512 thr. (Proven in R13: ~10us/layer, correct.)
__global__ __launch_bounds__(512) void k_tok2(const float* __restrict__ x, const float* __restrict__ states,
                                              const float* __restrict__ wq, const float* __restrict__ bq,
                                              const float* __restrict__ wk, const float* __restrict__ bk,
                                              const float2* __restrict__ fvG,
                                              const float* __restrict__ pTR, const float* __restrict__ pTI,
                                              const float* __restrict__ w_out, const float* __restrict__ b_out,
                                              const float* __restrict__ osc_p,
                                              const float* __restrict__ attn_s, const float* __restrict__ res_s,
                                              float* __restrict__ xout, unsigned short* __restrict__ xbf) {
  __shared__ __align__(16) float qrow[2][256];
  __shared__ __align__(16) float rkl[128], bkl[128];
  __shared__ float Psum[2][256];
  __shared__ float redm[2][4], reds[2][4];
  __shared__ float cred[2][256];
  __shared__ __align__(16) float xl[2][128];
  __shared__ __align__(16) float ctxl[2][128];
  __shared__ float uvU[2][512], uvV[2][512];
  __shared__ __align__(16) float4 part[2][8][32];
  __shared__ __align__(16) float2 fchunk[32][129];
  int blk = blockIdx.x;
  int b = blk >> 7, qp = blk & 127;
  int tid = threadIdx.x;
  int sub = tid >> 8, t = tid & 255;
  int q = qp * 2 + sub;
  // ---- phase A0: params, Q rows, x rows ----
  if (tid < 128) {
    rkl[tid] = INV2PI_F / (1.f + fabsf(wk[tid]));
    bkl[tid] = bk[tid] * INV2PI_F;
  }
  if (t < 128) {
    float xv = x[(b * cS + q) * cD + t];
    xl[sub][t] = xv;
    float rq = 1.f / (1.f + fabsf(wq[t]));
    float thq = fmaf(xv, rq, fmaf((float)q, PHI_F, bq[t])) * INV2PI_F;
    float fq = fract1(thq);
    qrow[sub][t]       = cos_rev(fq);
    qrow[sub][128 + t] = sin_rev(fq);
  }
  Psum[sub][t] = 0.f;
  __syncthreads();
  // ---- phase A1: scores (thread t = key position) ----
  bool act = (t <= q);
  float sc[8];
  const float4* Sr = (const float4*)(states + (b * cS + t) * cD);
#pragma unroll
  for (int h = 0; h < 8; ++h) {
    float sacc = 0.f;
#pragma unroll
    for (int j = 0; j < 4; ++j) {
      float4 sv4 = Sr[h * 4 + j];
      int hd = h * 16 + j * 4;
      float sva[4] = { sv4.x, sv4.y, sv4.z, sv4.w };
#pragma unroll
      for (int c = 0; c < 4; ++c) {
        float f = fract1(fmaf(sva[c], rkl[hd + c], bkl[hd + c]));
        float ck = cos_rev(f), sk = sin_rev(f);
        sacc = fmaf(qrow[sub][hd + c], ck, fmaf(qrow[sub][128 + hd + c], sk, sacc));
      }
    }
    sc[h] = act ? sacc * 0.17677669529663689f : -3.0e38f;   // 1/sqrt(2*DH)
  }
  // ---- phase A2: softmax ----
  int wid = t >> 6;
  for (int h = 0; h < 8; ++h) {
    float v = sc[h];
#pragma unroll
    for (int off = 32; off; off >>= 1) v = fmaxf(v, __shfl_xor(v, off, 64));
    if ((t & 63) == 0) redm[sub][wid] = v;
    __syncthreads();
    float m = fmaxf(fmaxf(redm[sub][0], redm[sub][1]), fmaxf(redm[sub][2], redm[sub][3]));
    float p = act ? __expf(sc[h] - m) : 0.f;
    float ps = p;
#pragma unroll
    for (int off = 32; off; off >>= 1) ps += __shfl_xor(ps, off, 64);
    if ((t & 63) == 0) reds[sub][wid] = ps;
    __syncthreads();
    float tot = reds[sub][0] + reds[sub][1] + reds[sub][2] + reds[sub][3];
    Psum[sub][t] += p / tot;
  }
  __syncthreads();
  // ---- phase A3: context -> ctxl ----
  {
    int d = t & 127, half = t >> 7;
    float acc = 0.f;
    int k0 = half * 128;
    int kend = min(k0 + 128, q + 1);
    for (int kk = k0; kk < kend; ++kk)
      acc = fmaf(Psum[sub][kk], states[(b * cS + kk) * cD + d], acc);
    cred[sub][t] = acc;
    __syncthreads();
    if (half == 0) ctxl[sub][d] = cred[sub][t] + cred[sub][t + 128];
  }
  // ---- phase B: fsum, 16 chunks of 32 n-rows; thread = (nl, tok, dq) ----
  {
    int nl  = tid >> 4;                             // 0..31
    int tok = (tid >> 3) & 1;
    int dq  = tid & 7;
    float srev = (float)(qp * 2 + tok) * INV2PI_F;
    for (int ch = 0; ch < 16; ++ch) {
      int n0 = ch * 32;
      const float2* src = fvG + n0 * cD;
#pragma unroll
      for (int i = 0; i < 8; ++i) {
        int idx = tid + i * 512;                    // 4096 = 32 rows x 128 d
        int r = idx >> 7, dcol = idx & 127;
        fchunk[r][dcol] = src[r * cD + dcol];
      }
      __syncthreads();
      float uc = 0.f, us = 0.f;
#pragma unroll
      for (int i = 0; i < 16; ++i) {
        int d = i * 8 + dq;
        float2 f = fchunk[nl][d];
        float fr = fract1(fmaf(xl[tok][d], f.x, f.y + srev));
        uc += cos_rev(fr);
        us += sin_rev(fr);
      }
      uc += __shfl_xor(uc, 1, 64); us += __shfl_xor(us, 1, 64);
      uc += __shfl_xor(uc, 2, 64); us += __shfl_xor(us, 2, 64);
      uc += __shfl_xor(uc, 4, 64); us += __shfl_xor(us, 4, 64);
      if (dq == 0) { uvU[tok][n0 + nl] = uc; uvV[tok][n0 + nl] = us; }
      __syncthreads();
    }
  }
  // ---- phase C: res projection + combine ----
  {
    int r8 = tid & 255;
    int d4 = r8 & 31, nh = r8 >> 5;                 // 8 n-chunks of 64
    float a0 = 0.f, a1 = 0.f, a2 = 0.f, a3 = 0.f;
    const float* prB = pTR + d4 * 4;
    const float* piB = pTI + d4 * 4;
    int n0 = nh * 64;
#pragma unroll 4
    for (int n = n0; n < n0 + 64; ++n) {
      float4 pr = *(const float4*)(prB + n * cD);
      float4 pi = *(const float4*)(piB + n * cD);
      float wr = uvU[sub][n], wi = uvV[sub][n];
      a0 = fmaf(wr, pr.x, fmaf(wi, pi.x, a0));
      a1 = fmaf(wr, pr.y, fmaf(wi, pi.y, a1));
      a2 = fmaf(wr, pr.z, fmaf(wi, pi.z, a2));
      a3 = fmaf(wr, pr.w, fmaf(wi, pi.w, a3));
    }
    part[sub][nh][d4] = make_float4(a0, a1, a2, a3);
    __syncthreads();
    if (nh == 0) {
      float rr[4] = { 0.f, 0.f, 0.f, 0.f };
#pragma unroll
      for (int j = 0; j < 8; ++j) {
        float4 p = part[sub][j][d4];
        rr[0] += p.x; rr[1] += p.y; rr[2] += p.z; rr[3] += p.w;
      }
      int di = d4 * 4;
      float4 cx  = *(const float4*)&ctxl[sub][di];
      float4 wo  = *(const float4*)(w_out + di);
      float4 bo  = *(const float4*)(b_out + di);
      float4 os4 = *(const float4*)(osc_p + di);
      float4 xv  = *(const float4*)&xl[sub][di];
      float as = attn_s[0], rs = res_s[0];
      float sphi = (float)q * PHI_F;
      float cxa[4] = { cx.x, cx.y, cx.z, cx.w };
      float woa[4] = { wo.x, wo.y, wo.z, wo.w };
      float boa[4] = { bo.x, bo.y, bo.z, bo.w };
      float osa[4] = { os4.x, os4.y, os4.z, os4.w };
      float xva[4] = { xv.x, xv.y, xv.z, xv.w };
      float oa[4];
#pragma unroll
      for (int c = 0; c < 4; ++c) {
        float th = fmaf(cxa[c], 1.f / (1.f + fabsf(woa[c])), boa[c]) + sphi;
        float f = fract1(th * INV2PI_F);
        float ao = osa[c] * (cos_rev(f) + sin_rev(f));
        float r = rr[c];
        float sil = r / (1.f + __expf(-r));
        oa[c] = fmaf(as, ao, fmaf(rs, sil, xva[c]));
      }
      *(float4*)(xout + (b * cS + q) * cD + di) = make_float4(oa[0], oa[1], oa[2], oa[3]);
      if (xbf) {
        ushort4 b4 = { f2bf(oa[0]), f2bf(oa[1]), f2bf(oa[2]), f2bf(oa[3]) };
        *(ushort4*)(xbf + (b * cS + q) * cD + di) = b4;
      }
    }
  }
}

// ---------------- final logits GEMM: R9 champion (G*) ------------------------
__global__ __launch_bounds__(256) void k_gemm(const unsigned short* __restrict__ Xbf,
                                              const unsigned short* __restrict__ Wbf,
                                              float* __restrict__ out) {
  __shared__ __align__(16) float Cst[4][16 * 132];
  int t = threadIdx.x;
  int mchunk = blockIdx.x / 99, vchunk = blockIdx.x % 99;
  int m0 = mchunk * 64;
  int v0 = vchunk * 512;
  int wid = t >> 6, lane = t & 63, lr = lane & 15, lk = lane >> 4;
  int wv = wid * 128;
  const bf16x8* Xp = (const bf16x8*)Xbf;            // row-major: row*16 + ks*4 + lk
  const bf16x8* Wp = (const bf16x8*)Wbf;
  f32x4 acc[4][8];
#pragma unroll
  for (int fm = 0; fm < 4; ++fm)
#pragma unroll
    for (int fv = 0; fv < 8; ++fv) acc[fm][fv] = (f32x4){0.f, 0.f, 0.f, 0.f};
#pragma unroll
  for (int ks = 0; ks < 4; ++ks) {
    bf16x8 a[4];
#pragma unroll
    for (int fm = 0; fm < 4; ++fm)
      a[fm] = Xp[(m0 + fm * 16 + lr) * 16 + ks * 4 + lk];
#pragma unroll
    for (int fv = 0; fv < 8; ++fv) {
      bf16x8 b = Wp[(size_t)(v0 + wv + fv * 16 + lr) * 16 + ks * 4 + lk];
#pragma unroll
      for (int fm = 0; fm < 4; ++fm)
        acc[fm][fv] = __builtin_amdgcn_mfma_f32_16x16x32_bf16(a[fm], b, acc[fm][fv], 0, 0, 0);
    }
  }
  float* Cp = &Cst[wid][0];
  int row2b = lane >> 5;
  int colg  = (lane & 31) * 4;
#pragma unroll
  for (int fm = 0; fm < 4; ++fm) {
#pragma unroll
    for (int fv = 0; fv < 8; ++fv)
#pragma unroll
      for (int r = 0; r < 4; ++r)
        Cp[(lk * 4 + r) * 132 + fv * 16 + lr] = acc[fm][fv][r];
#pragma unroll
    for (int step = 0; step < 8; ++step) {
      int rowl = step * 2 + row2b;
      float4 cv = *(const float4*)&Cp[rowl * 132 + colg];
      size_t rb = (size_t)(m0 + fm * 16 + rowl) * cV;
      int cb = v0 + wv + colg;
      if (cb + 3 < cV) {
        *(float4*)(out + rb + cb) = cv;
      } else {
        float ca[4] = { cv.x, cv.y, cv.z, cv.w };
#pragma unroll
        for (int j = 0; j < 4; ++j)
          if (cb + j < cV) out[rb + cb + j] = ca[j];
      }
    }
  }
}

extern "C" void kernel_launch(void* const* d_in, const int* in_sizes, int n_in,
                              void* d_out, int out_size, void* d_ws, size_t ws_size,
                              hipStream_t stream) {
  const int*   tokens    = (const int*)d_in[0];
  const float* emb       = (const float*)d_in[1];
  const float* wq        = (const float*)d_in[2];
  const float* bq        = (const float*)d_in[3];
  const float* wk        = (const float*)d_in[4];
  const float* bk        = (const float*)d_in[5];
  const float* w_out     = (const float*)d_in[6];
  const float* b_out     = (const float*)d_in[7];
  const float* out_scale = (const float*)d_in[8];
  const float* Wf        = (const float*)d_in[9];
  const float* Bf        = (const float*)d_in[10];
  const float* pr        = (const float*)d_in[11];
  const float* pi        = (const float*)d_in[12];
  const float* attn_s    = (const float*)d_in[13];
  const float* res_s     = (const float*)d_in[14];
  const float* out_proj  = (const float*)d_in[15];
  float* out = (float*)d_out;
  float* ws  = (float*)d_ws;

  float*  states = ws;                          // 65536
  float*  x1     = ws + 65536;                  // 65536
  float*  x2     = ws + 131072;                 // 65536
  float*  pTR    = ws + 196608;                 // 131072
  float*  pTI    = ws + 327680;                 // 131072
  float2* fvG    = (float2*)(ws + 458752);      // 131072 float2 (262144 floats)
  float2* mc     = (float2*)(ws + 720896);      // 65536 float2 (131072 floats)
  unsigned short* X2bf = (unsigned short*)(ws + 851968);  // 65536 ushorts
  unsigned short* Wbf  = (unsigned short*)(ws + 884736);  // 50688*128 ushorts (13.0MB)

  k_setup<<<832 + (cVp * 16) / 256, 256, 0, stream>>>(tokens, emb, mc, pr, pi, pTR, pTI,
                                                      Wf, Bf, fvG, out_proj, Wbf);
  k_scan<<<1, 256, 0, stream>>>(mc, states);

  const float* xin = states;
  float* xouts[2] = { x1, x2 };
  for (int l = 0; l < 2; ++l) {
    k_tok2<<<256, 512, 0, stream>>>(xin, states,
                                    wq + l * 128, bq + l * 128, wk + l * 128, bk + l * 128,
                                    fvG + l * 65536,
                                    pTR + l * 65536, pTI + l * 65536,
                                    w_out + l * 128, b_out + l * 128, out_scale + l * 128,
                                    attn_s + l, res_s + l,
                                    xouts[l], (l == 1) ? X2bf : (unsigned short*)nullptr);
    xin = xouts[l];
  }
  k_gemm<<<8 * 99, 256, 0, stream>>>(X2bf, Wbf, out);
}